// Round 12
// baseline (187.662 us; speedup 1.0000x reference)
//
#include <hip/hip_runtime.h>
#include <hip/hip_fp16.h>
#include <stdint.h>

#define NROWS 8192   // B*S
#define HDIM  128
#define KSUB  8
#define NC    4096
#define DSUB  16
#define OUTD  6

#define FB_TAU 3e-4f                // fallback margin; split-fp16 distance error bound ~4e-5

typedef _Float16 f16x8 __attribute__((ext_vector_type(8)));
typedef float    f32x16 __attribute__((ext_vector_type(16)));

// ws layout (bytes): total 8,519,680
#define XK_OFF 0u            // xk:   [KSUB][NROWS][DSUB] fp32, 4 MiB
#define CN_OFF 4194304u      // cnorm:[KSUB][NC] fp32, 128 KiB
#define B2_OFF 4325376u      // B2S:  [KSUB][128 units][2 halves][64 lanes] f16x8 (NEGATED), 2 MiB
#define PK_OFF 6422528u      // pk:   [4 splits][NROWS][KSUB] u64, 2 MiB

// ---------------- Kernel 1: prep = MLP + cnorm + bprep (256 blocks) ----------------
__global__ __launch_bounds__(256) void prep_kernel(
    const float* __restrict__ z, const float* __restrict__ W1, const float* __restrict__ b1,
    const float* __restrict__ W2, const float* __restrict__ b2,
    const float* __restrict__ ce,
    float* __restrict__ xk, float* __restrict__ cnorm, f16x8* __restrict__ B2S)
{
    __shared__ float h1s[32 * HDIM];    // 16 KiB
    __shared__ float w2s[HDIM * HDIM];  // 64 KiB
    const int t = threadIdx.x;
    const int row0 = blockIdx.x * 32;

    // ---- bprep for 32x32x16 MFMA: entry e = (k, unit, half, lane) ----
    // Stores hi/lo split of (-16*c): A.B = -4096*dot, so with C init 2048*nrm
    // the MFMA emits 2048*(nrm - 2*dot) directly (all pow2-exact).
    #pragma unroll
    for (int q = 0; q < 2; ++q) {
        const int e = blockIdx.x * 512 + q * 256 + t;    // 0..131071
        const int k    = e >> 14;
        const int unit = (e >> 7) & 127;
        const int half = (e >> 6) & 1;
        const int lane = e & 63;
        const int n    = unit * 32 + (lane & 31);
        const int dims = (lane >> 5) * 8;
        const float* cp = &ce[((size_t)k * NC + n) * DSUB + dims];
        f16x8 hi, lo;
        #pragma unroll
        for (int j = 0; j < 8; ++j) {
            const float s = cp[j] * -16.0f;              // pow2 scale (negated), lo stays normal
            const _Float16 h = (_Float16)s;
            hi[j] = h;
            lo[j] = (_Float16)(s - (float)h);
        }
        B2S[e] = half ? lo : hi;
    }

    // centroid norms (first 128 blocks cover KSUB*NC = 32768 centroids)
    if (blockIdx.x < (KSUB * NC) / 256) {
        const int g = blockIdx.x * 256 + t;
        const float4* cp = (const float4*)&ce[(size_t)g * DSUB];
        float nn = 0.f;
        #pragma unroll
        for (int q = 0; q < 4; ++q) {
            const float4 v = cp[q];
            nn = fmaf(v.x, v.x, nn); nn = fmaf(v.y, v.y, nn);
            nn = fmaf(v.z, v.z, nn); nn = fmaf(v.w, v.w, nn);
        }
        cnorm[g] = nn;
    }

    // stage W2 (coalesced)
    {
        const float4* g4 = (const float4*)W2;
        float4* s4 = (float4*)w2s;
        #pragma unroll
        for (int q = 0; q < 16; ++q) s4[t + q * 256] = g4[t + q * 256];
    }

    // phase A: h1 = relu(z @ W1 + b1) into LDS (32x128)
    #pragma unroll
    for (int e = 0; e < 16; ++e) {
        const int idx = e * 256 + t;
        const int r = idx >> 7, j = idx & 127;
        const int n = row0 + r;
        float acc = b1[j];
        acc = fmaf(z[n * 3 + 0], W1[0 * HDIM + j], acc);
        acc = fmaf(z[n * 3 + 1], W1[1 * HDIM + j], acc);
        acc = fmaf(z[n * 3 + 2], W1[2 * HDIM + j], acc);
        h1s[idx] = fmaxf(acc, 0.f);
    }
    __syncthreads();

    // phase B: 4 rows x 4 cols per thread
    const int c4 = (t & 31) * 4;
    const int r4 = (t >> 5) * 4;
    float acc[4][4];
    #pragma unroll
    for (int a = 0; a < 4; ++a)
        #pragma unroll
        for (int b = 0; b < 4; ++b) acc[a][b] = 0.f;

    for (int k4 = 0; k4 < HDIM; k4 += 4) {
        float hh[4][4], ww[4][4];
        #pragma unroll
        for (int q = 0; q < 4; ++q) {
            const float4 v = *(const float4*)&h1s[(r4 + q) * HDIM + k4];
            hh[q][0] = v.x; hh[q][1] = v.y; hh[q][2] = v.z; hh[q][3] = v.w;
        }
        #pragma unroll
        for (int p = 0; p < 4; ++p) {
            const float4 v = *(const float4*)&w2s[(k4 + p) * HDIM + c4];
            ww[p][0] = v.x; ww[p][1] = v.y; ww[p][2] = v.z; ww[p][3] = v.w;
        }
        #pragma unroll
        for (int q = 0; q < 4; ++q)
            #pragma unroll
            for (int p = 0; p < 4; ++p) {
                acc[q][0] = fmaf(hh[q][p], ww[p][0], acc[q][0]);
                acc[q][1] = fmaf(hh[q][p], ww[p][1], acc[q][1]);
                acc[q][2] = fmaf(hh[q][p], ww[p][2], acc[q][2]);
                acc[q][3] = fmaf(hh[q][p], ww[p][3], acc[q][3]);
            }
    }

    const float4 bb = *(const float4*)&b2[c4];
    const int kk = c4 >> 4;
    const int dd = c4 & 15;
    #pragma unroll
    for (int q = 0; q < 4; ++q) {
        float4 o;
        o.x = fmaxf(acc[q][0] + bb.x, 0.f);
        o.y = fmaxf(acc[q][1] + bb.y, 0.f);
        o.z = fmaxf(acc[q][2] + bb.z, 0.f);
        o.w = fmaxf(acc[q][3] + bb.w, 0.f);
        *(float4*)&xk[((size_t)kk * NROWS + (row0 + r4 + q)) * DSUB + dd] = o;
    }
}

// ---------------- Kernel 2: MFMA 32x32 argmin (TLP + double-buffered) ----------------
// grid (64 rowblocks, 8 k, 4 cz) = 2048 blocks. Each block: 32 units (1024
// centroids) in 4 chunks of 8, double-buffered: prefetch next chunk into regs
// BEFORE computing current, write regs->other LDS buffer after. Load latency
// hidden behind ~2.6K cyc of compute; barriers pay only the lgkm drain.
// LDS 36 KiB -> 4 blocks/CU; VGPR ~111 < 128 cap.
__global__ __launch_bounds__(256, 4) void argmin_kernel(
    const float* __restrict__ xk, const f16x8* __restrict__ B2S,
    const float* __restrict__ cnorm, unsigned long long* __restrict__ pk)
{
    __shared__ f16x8 cs[2][8 * 2 * 64];  // 2 x 16 KiB
    __shared__ float cnS[1024];          // 4 KiB: norms * 2048 for this split
    const int t = threadIdx.x;
    const int lane = t & 63;
    const int wid  = t >> 6;
    const int k  = blockIdx.y;                 // 0..7
    const int cz = blockIdx.z;                 // 0..3
    const int rowbase = blockIdx.x * 128 + wid * 32;
    const int col = lane & 31;
    const int khl = lane >> 5;                 // which K-half this lane holds

    // stage the 1024 norms of this split, pre-scaled by 2048 (pow2-exact)
    {
        const float* cnp0 = &cnorm[k * NC + cz * 1024];
        #pragma unroll
        for (int q = 0; q < 4; ++q) cnS[t + q * 256] = cnp0[t + q * 256] * 2048.0f;
    }

    // A fragments: 32 rows, A[m=lane&31][kd=(lane>>5)*8+j], hi/lo split (exact)
    f16x8 Ah, Al;
    {
        const float* xp = &xk[((size_t)k * NROWS + rowbase + col) * DSUB + khl * 8];
        #pragma unroll
        for (int j = 0; j < 8; ++j) {
            const float s = xp[j] * 256.0f;
            const _Float16 h = (_Float16)s;
            Ah[j] = h;
            Al[j] = (_Float16)(s - (float)h);
        }
    }

    float m1[16], m2[16];
    int   idx[16];
    #pragma unroll
    for (int r = 0; r < 16; ++r) { m1[r] = 1e30f; m2[r] = 1e30f; idx[r] = 0; }

    // block's B slice: 32 units = 4096 uint4; chunk = 8 units = 1024 uint4
    const uint4* gB = (const uint4*)&B2S[((size_t)(k * 128 + cz * 32)) * 128];

    // prestage chunk 0
    uint4 pf[4];
    #pragma unroll
    for (int q = 0; q < 4; ++q) pf[q] = gB[t + q * 256];
    {
        uint4* s4 = (uint4*)cs[0];
        #pragma unroll
        for (int q = 0; q < 4; ++q) s4[t + q * 256] = pf[q];
    }
    __syncthreads();

    for (int ch = 0; ch < 4; ++ch) {
        // prefetch next chunk into regs (overlaps with compute below)
        if (ch < 3) {
            const uint4* gp = gB + (ch + 1) * 1024;
            #pragma unroll
            for (int q = 0; q < 4; ++q) pf[q] = gp[t + q * 256];
        }

        const f16x8* buf = cs[ch & 1];
        #pragma unroll 2
        for (int u = 0; u < 8; ++u) {
            const f16x8 Bh = buf[u * 128 + lane];
            const f16x8 Bl = buf[u * 128 + 64 + lane];
            const float nrmS = cnS[(ch * 8 + u) * 32 + col];
            f32x16 acc;
            #pragma unroll
            for (int r = 0; r < 16; ++r) acc[r] = nrmS;   // C init = 2048*nrm
            acc = __builtin_amdgcn_mfma_f32_32x32x16_f16(Ah, Bh, acc, 0, 0, 0);
            acc = __builtin_amdgcn_mfma_f32_32x32x16_f16(Al, Bl, acc, 0, 0, 0);
            acc = __builtin_amdgcn_mfma_f32_32x32x16_f16(Ah, Bl, acc, 0, 0, 0);
            acc = __builtin_amdgcn_mfma_f32_32x32x16_f16(Al, Bh, acc, 0, 0, 0);
            // acc[r] = 2048*(nrm - 2*dot)  -- scaled distance, order-preserved
            const int c = cz * 1024 + (ch * 8 + u) * 32 + col;
            #pragma unroll
            for (int r = 0; r < 16; ++r) {
                const float s = acc[r];
                const bool lt = s < m1[r];
                m2[r] = __builtin_amdgcn_fmed3f(s, m1[r], m2[r]);
                idx[r] = lt ? c : idx[r];
                m1[r] = fminf(s, m1[r]);
            }
        }

        if (ch < 3) {
            __syncthreads();   // all waves done computing ch (so done reading buf[(ch+1)&1])
            uint4* s4 = (uint4*)cs[(ch + 1) & 1];
            #pragma unroll
            for (int q = 0; q < 4; ++q) s4[t + q * 256] = pf[q];
            __syncthreads();   // writes visible before next chunk's compute
        }
    }

    // reduce across the 32 col-lanes holding each row (xor 1,2,4,8,16)
    #pragma unroll
    for (int off = 1; off < 32; off <<= 1) {
        #pragma unroll
        for (int r = 0; r < 16; ++r) {
            const float om1 = __shfl_xor(m1[r], off, 64);
            const float om2 = __shfl_xor(m2[r], off, 64);
            const int  oidx = __shfl_xor(idx[r], off, 64);
            const bool better = (om1 < m1[r]) ||
                                (om1 == m1[r] && oidx < idx[r]);
            m2[r] = fminf(fminf(m2[r], om2), fmaxf(m1[r], om1));
            m1[r] = better ? om1 : m1[r];
            idx[r] = better ? oidx : idx[r];
        }
    }

    if (col == 0) {   // lanes 0 and 32 hold final results for their 16 rows
        #pragma unroll
        for (int r = 0; r < 16; ++r) {
            const int row = rowbase + (r & 3) + 8 * (r >> 2) + 4 * khl;
            const float m1t = m1[r] * (1.0f / 2048.0f);   // unscale (pow2-exact)
            unsigned u = __float_as_uint(m1t);
            u = (u & 0x80000000u) ? ~u : (u | 0x80000000u);      // order-preserving
            const unsigned short dh = __half_as_ushort(
                __float2half((m2[r] - m1[r]) * (1.0f / 2048.0f)));
            pk[((size_t)cz * NROWS + row) * KSUB + k] =
                ((unsigned long long)u << 32) |
                ((unsigned)dh << 16) | (unsigned)idx[r];
        }
    }
}

// ---------------- Kernel 3: finish = merge 4 splits + exact rescue + LUT output --------
__global__ __launch_bounds__(256) void finish_kernel(
    const float* __restrict__ xk, const float* __restrict__ ce,
    const float* __restrict__ cnorm, const unsigned long long* __restrict__ pk,
    const float* __restrict__ W3, const float* __restrict__ b3,
    float* __restrict__ out)
{
    __shared__ int codes_s[256];
    __shared__ int wl_s[256];
    __shared__ int wcnt;
    const int t = threadIdx.x;
    const int row0 = blockIdx.x * 32;
    if (t == 0) wcnt = 0;
    __syncthreads();

    // merge 4 splits for (row, k) = (row0 + t>>3, t&7)
    {
        const int row = row0 + (t >> 3);
        const int k = t & 7;
        unsigned long long p[4];
        #pragma unroll
        for (int s = 0; s < 4; ++s)
            p[s] = pk[((size_t)s * NROWS + row) * KSUB + k];
        unsigned long long w = p[0];
        #pragma unroll
        for (int s = 1; s < 4; ++s) w = p[s] < w ? p[s] : w;
        const unsigned uw = (unsigned)(w >> 32);
        const float m1w = __uint_as_float((uw & 0x80000000u) ? (uw ^ 0x80000000u) : ~uw);
        float m2g = m1w + (float)__ushort_as_half((unsigned short)((unsigned)w >> 16));
        #pragma unroll
        for (int s = 0; s < 4; ++s) {
            if (p[s] != w) {   // splits have disjoint idx ranges -> pk values unique
                const unsigned us = (unsigned)(p[s] >> 32);
                m2g = fminf(m2g, __uint_as_float(
                    (us & 0x80000000u) ? (us ^ 0x80000000u) : ~us));
            }
        }
        codes_s[t] = (int)(w & 0xFFFFull);
        if (m2g - m1w < FB_TAU) {      // near-tie: exact fp32 rescan needed
            const int slot = atomicAdd(&wcnt, 1);
            wl_s[slot] = t;
        }
    }
    __syncthreads();

    // exact fp32 rescue, wave-per-item over the block-local worklist
    {
        const int lane = t & 63;
        const int wid = t >> 6;
        const int nitems = wcnt;
        for (int i = wid; i < nitems; i += 4) {
            const int wg = wl_s[i];
            const int row = row0 + (wg >> 3), k = wg & 7;
            float xr[DSUB];
            {
                const float* xp = &xk[((size_t)k * NROWS + row) * DSUB];
                #pragma unroll
                for (int q = 0; q < DSUB; q += 4) {
                    const float4 v = *(const float4*)&xp[q];
                    xr[q + 0] = -2.f * v.x; xr[q + 1] = -2.f * v.y;
                    xr[q + 2] = -2.f * v.z; xr[q + 3] = -2.f * v.w;
                }
            }
            float bm = 1e30f; int bi = NC;
            for (int c = lane; c < NC; c += 64) {
                const float* cp = &ce[((size_t)k * NC + c) * DSUB];
                float s = cnorm[k * NC + c];
                #pragma unroll
                for (int d = 0; d < DSUB; ++d) s = fmaf(xr[d], cp[d], s);
                if (s < bm) { bm = s; bi = c; }
            }
            #pragma unroll
            for (int off = 1; off < 64; off <<= 1) {
                const float om = __shfl_xor(bm, off, 64);
                const int  oi = __shfl_xor(bi, off, 64);
                const bool better = (om < bm) || (om == bm && oi < bi);
                bm = better ? om : bm;
                bi = better ? oi : bi;
            }
            if (lane == 0) codes_s[wg] = bi;
        }
    }
    __syncthreads();

    // output: 32 rows x 6 = 192 outputs
    if (t < 32 * OUTD) {
        const int nl = t / OUTD;
        const int o = t - nl * OUTD;
        const int n = row0 + nl;
        float acc = b3[o];
        #pragma unroll
        for (int k = 0; k < KSUB; ++k) {
            const int code = codes_s[nl * KSUB + k];
            const float* cp = &ce[((size_t)k * NC + code) * DSUB];
            const float* wp = &W3[(k * DSUB) * OUTD + o];
            #pragma unroll
            for (int d = 0; d < DSUB; ++d)
                acc = fmaf(cp[d], wp[d * OUTD], acc);
        }
        out[n * OUTD + o] = acc;
    }
}

extern "C" void kernel_launch(void* const* d_in, const int* in_sizes, int n_in,
                              void* d_out, int out_size, void* d_ws, size_t ws_size,
                              hipStream_t stream)
{
    const float* z  = (const float*)d_in[0];
    const float* W1 = (const float*)d_in[1];
    const float* b1 = (const float*)d_in[2];
    const float* W2 = (const float*)d_in[3];
    const float* b2 = (const float*)d_in[4];
    const float* ce = (const float*)d_in[5];
    const float* W3 = (const float*)d_in[6];
    const float* b3 = (const float*)d_in[7];

    char* ws = (char*)d_ws;
    float* xk    = (float*)(ws + XK_OFF);
    float* cnorm = (float*)(ws + CN_OFF);
    f16x8* B2S   = (f16x8*)(ws + B2_OFF);
    unsigned long long* pk = (unsigned long long*)(ws + PK_OFF);

    hipLaunchKernelGGL(prep_kernel, dim3(256), dim3(256), 0, stream,
                       z, W1, b1, W2, b2, ce, xk, cnorm, B2S);
    hipLaunchKernelGGL(argmin_kernel, dim3(64, 8, 4), dim3(256), 0, stream,
                       xk, B2S, cnorm, pk);
    hipLaunchKernelGGL(finish_kernel, dim3(256), dim3(256), 0, stream,
                       xk, ce, cnorm, pk, W3, b3, (float*)d_out);
}

// Round 13
// 168.423 us; speedup vs baseline: 1.1142x; 1.1142x over previous
//
#include <hip/hip_runtime.h>
#include <hip/hip_fp16.h>
#include <stdint.h>

#define NROWS 8192   // B*S
#define HDIM  128
#define KSUB  8
#define NC    4096
#define DSUB  16
#define OUTD  6

#define FB_TAU 6e-5f                // fallback margin; split-fp16 distance error bound ~1.5e-5
#define DOTSCALE (-2.0f / 4096.0f)  // undo x*256, c*16 scaling; exact pow2

typedef _Float16 f16x8 __attribute__((ext_vector_type(8)));
typedef float    f32x4 __attribute__((ext_vector_type(4)));

// ws layout (bytes): total 8,519,680
#define XK_OFF 0u            // xk:   [KSUB][NROWS][DSUB] fp32, 4 MiB
#define CN_OFF 4194304u      // cnorm:[KSUB][NC] fp32, 128 KiB
#define B1_OFF 4325376u      // B1S:  [KSUB][256 tiles][64 lanes] f16x8, 2 MiB
#define PK_OFF 6422528u      // pk:   [4 splits][NROWS][KSUB] u64, 2 MiB

// ---------------- Kernel 1: prep = MLP + cnorm + bprep (512 blocks, 16 rows each) ------
__global__ __launch_bounds__(256) void prep_kernel(
    const float* __restrict__ z, const float* __restrict__ W1, const float* __restrict__ b1,
    const float* __restrict__ W2, const float* __restrict__ b2,
    const float* __restrict__ ce,
    float* __restrict__ xk, float* __restrict__ cnorm, f16x8* __restrict__ B1S)
{
    __shared__ float h1s[16 * HDIM];    // 8 KiB
    __shared__ float w2s[HDIM * HDIM];  // 64 KiB
    const int t = threadIdx.x;
    const int row0 = blockIdx.x * 16;

    // ---- bprep: one 16x16-tile fragment per thread (512 x 256 = 131072 entries) ----
    // entry e = (k, tile, lane); quad<2 -> hi, quad>=2 -> lo (B2 = B1[lane^32]).
    {
        const int e = blockIdx.x * 256 + t;
        const int k    = e >> 14;
        const int tile = (e >> 6) & 255;
        const int lane = e & 63;
        const int col  = lane & 15;
        const int quad = lane >> 4;
        const int dims = (quad & 1) * 8;
        const int part = quad >> 1;                      // 0: hi half of K, 1: lo half
        const int n = tile * 16 + col;
        const float* cp = &ce[((size_t)k * NC + n) * DSUB + dims];
        f16x8 hi, lo;
        #pragma unroll
        for (int j = 0; j < 8; ++j) {
            const float s = cp[j] * 16.0f;               // pow2 scale keeps lo normal
            const _Float16 h = (_Float16)s;
            hi[j] = h;
            lo[j] = (_Float16)(s - (float)h);
        }
        B1S[e] = part ? lo : hi;
    }

    // centroid norms (first 128 blocks cover KSUB*NC = 32768 centroids)
    if (blockIdx.x < (KSUB * NC) / 256) {
        const int g = blockIdx.x * 256 + t;
        const float4* cp = (const float4*)&ce[(size_t)g * DSUB];
        float nn = 0.f;
        #pragma unroll
        for (int q = 0; q < 4; ++q) {
            const float4 v = cp[q];
            nn = fmaf(v.x, v.x, nn); nn = fmaf(v.y, v.y, nn);
            nn = fmaf(v.z, v.z, nn); nn = fmaf(v.w, v.w, nn);
        }
        cnorm[g] = nn;
    }

    // stage W2 (coalesced)
    {
        const float4* g4 = (const float4*)W2;
        float4* s4 = (float4*)w2s;
        #pragma unroll
        for (int q = 0; q < 16; ++q) s4[t + q * 256] = g4[t + q * 256];
    }

    // phase A: h1 = relu(z @ W1 + b1) into LDS (16x128)
    #pragma unroll
    for (int e = 0; e < 8; ++e) {
        const int idx = e * 256 + t;
        const int r = idx >> 7, j = idx & 127;
        const int n = row0 + r;
        float acc = b1[j];
        acc = fmaf(z[n * 3 + 0], W1[0 * HDIM + j], acc);
        acc = fmaf(z[n * 3 + 1], W1[1 * HDIM + j], acc);
        acc = fmaf(z[n * 3 + 2], W1[2 * HDIM + j], acc);
        h1s[idx] = fmaxf(acc, 0.f);
    }
    __syncthreads();

    // phase B: 2 rows x 4 cols per thread (same per-output fma chain as before)
    const int c4 = (t & 31) * 4;
    const int r2 = (t >> 5) * 2;
    float acc[2][4];
    #pragma unroll
    for (int a = 0; a < 2; ++a)
        #pragma unroll
        for (int b = 0; b < 4; ++b) acc[a][b] = 0.f;

    for (int k4 = 0; k4 < HDIM; k4 += 4) {
        float hh[2][4], ww[4][4];
        #pragma unroll
        for (int q = 0; q < 2; ++q) {
            const float4 v = *(const float4*)&h1s[(r2 + q) * HDIM + k4];
            hh[q][0] = v.x; hh[q][1] = v.y; hh[q][2] = v.z; hh[q][3] = v.w;
        }
        #pragma unroll
        for (int p = 0; p < 4; ++p) {
            const float4 v = *(const float4*)&w2s[(k4 + p) * HDIM + c4];
            ww[p][0] = v.x; ww[p][1] = v.y; ww[p][2] = v.z; ww[p][3] = v.w;
        }
        #pragma unroll
        for (int q = 0; q < 2; ++q)
            #pragma unroll
            for (int p = 0; p < 4; ++p) {
                acc[q][0] = fmaf(hh[q][p], ww[p][0], acc[q][0]);
                acc[q][1] = fmaf(hh[q][p], ww[p][1], acc[q][1]);
                acc[q][2] = fmaf(hh[q][p], ww[p][2], acc[q][2]);
                acc[q][3] = fmaf(hh[q][p], ww[p][3], acc[q][3]);
            }
    }

    const float4 bb = *(const float4*)&b2[c4];
    const int kk = c4 >> 4;
    const int dd = c4 & 15;
    #pragma unroll
    for (int q = 0; q < 2; ++q) {
        float4 o;
        o.x = fmaxf(acc[q][0] + bb.x, 0.f);
        o.y = fmaxf(acc[q][1] + bb.y, 0.f);
        o.z = fmaxf(acc[q][2] + bb.z, 0.f);
        o.w = fmaxf(acc[q][3] + bb.w, 0.f);
        *(float4*)&xk[((size_t)kk * NROWS + (row0 + r2 + q)) * DSUB + dd] = o;
    }
}

// ---------------- Kernel 2: MFMA 16x16 argmin (r9 structure, occupancy-doubled) --------
// grid (64, 8 k, 4 cz) = 2048 blocks. LDS = 8 KiB chunk (8 tiles) + 4 KiB norms
// = 12.5 KiB; __launch_bounds__(256,8) -> 8 blocks/CU, 32 waves/CU (r9 was 4
// blocks/CU, 48% occupancy, latency-bound at 75 us; no pipe was saturated).
// VGPR 36 measured in r9 << 64 cap -> no spill risk.
__global__ __launch_bounds__(256, 8) void argmin_kernel(
    const float* __restrict__ xk, const f16x8* __restrict__ B1S,
    const float* __restrict__ cnorm, unsigned long long* __restrict__ pk)
{
    __shared__ f16x8 cs[8 * 64];    // 8 KiB = 8 tiles
    __shared__ float cnL[1024];     // 4 KiB = norms for this (k, cz)
    const int t = threadIdx.x;
    const int lane = t & 63;
    const int wid  = t >> 6;
    const int k  = blockIdx.y;                 // 0..7
    const int cz = blockIdx.z;                 // 0..3
    const int rb = blockIdx.x * 4 + wid;       // 0..255 (32-row block)
    const int col  = lane & 15;
    const int quad = lane >> 4;
    const int dims = (quad & 1) * 8;
    const int part = quad >> 1;

    // stage the 1024 norms of this centroid split (once)
    {
        const float* cnp0 = &cnorm[k * NC + cz * 1024];
        #pragma unroll
        for (int q = 0; q < 4; ++q) cnL[t + q * 256] = cnp0[t + q * 256];
    }

    // A fragments for 2 groups of 16 rows (hi/lo split, exact)
    f16x8 A[2];
    #pragma unroll
    for (int g = 0; g < 2; ++g) {
        const int row = rb * 32 + g * 16 + col;
        const float* xp = &xk[((size_t)k * NROWS + row) * DSUB + dims];
        f16x8 hi, lo;
        #pragma unroll
        for (int j = 0; j < 8; ++j) {
            const float s = xp[j] * 256.0f;
            const _Float16 h = (_Float16)s;
            hi[j] = h;
            lo[j] = (_Float16)(s - (float)h);
        }
        A[g] = part ? lo : hi;
    }

    float m1[2][4], m2[2][4];
    int   idx[2][4];
    #pragma unroll
    for (int g = 0; g < 2; ++g)
        #pragma unroll
        for (int j = 0; j < 4; ++j) { m1[g][j] = 1e30f; m2[g][j] = 1e30f; idx[g][j] = 0; }

    const f16x8* gp = &B1S[((size_t)k * 256 + cz * 64) * 64];

    for (int ch = 0; ch < 8; ++ch) {
        __syncthreads();                       // previous chunk consumed (covers cnL 1st iter)
        {   // stage 8 tiles (8 KiB): 512 uint4, 2 per thread, coalesced
            const uint4* g4 = (const uint4*)(gp + (size_t)ch * 512);
            uint4* s4 = (uint4*)cs;
            #pragma unroll
            for (int q = 0; q < 2; ++q) s4[t + q * 256] = g4[t + q * 256];
        }
        __syncthreads();

        #pragma unroll 2
        for (int tt = 0; tt < 8; ++tt) {
            const f16x8 b1 = cs[tt * 64 + lane];
            const f16x8 b2 = cs[tt * 64 + (lane ^ 32)];   // part-flipped partner
            const float nrm = cnL[(ch * 8 + tt) * 16 + col];  // 16 words, broadcast
            const f32x4 zz = {0.f, 0.f, 0.f, 0.f};
            f32x4 p0 = __builtin_amdgcn_mfma_f32_16x16x32_f16(A[0], b1, zz, 0, 0, 0);
            p0       = __builtin_amdgcn_mfma_f32_16x16x32_f16(A[0], b2, p0, 0, 0, 0);
            f32x4 p1 = __builtin_amdgcn_mfma_f32_16x16x32_f16(A[1], b1, zz, 0, 0, 0);
            p1       = __builtin_amdgcn_mfma_f32_16x16x32_f16(A[1], b2, p1, 0, 0, 0);
            const int c = ((cz * 64 + ch * 8 + tt) << 4) + col;
            #pragma unroll
            for (int j = 0; j < 4; ++j) {
                {
                    const float s = fmaf(p0[j], DOTSCALE, nrm);
                    const bool lt = s < m1[0][j];
                    m2[0][j] = __builtin_amdgcn_fmed3f(s, m1[0][j], m2[0][j]);
                    idx[0][j] = lt ? c : idx[0][j];
                    m1[0][j] = fminf(s, m1[0][j]);
                }
                {
                    const float s = fmaf(p1[j], DOTSCALE, nrm);
                    const bool lt = s < m1[1][j];
                    m2[1][j] = __builtin_amdgcn_fmed3f(s, m1[1][j], m2[1][j]);
                    idx[1][j] = lt ? c : idx[1][j];
                    m1[1][j] = fminf(s, m1[1][j]);
                }
            }
        }
    }

    // reduce across the 16 lanes of each quad
    #pragma unroll
    for (int off = 1; off < 16; off <<= 1) {
        #pragma unroll
        for (int g = 0; g < 2; ++g)
            #pragma unroll
            for (int j = 0; j < 4; ++j) {
                const float om1 = __shfl_xor(m1[g][j], off, 64);
                const float om2 = __shfl_xor(m2[g][j], off, 64);
                const int  oidx = __shfl_xor(idx[g][j], off, 64);
                const bool better = (om1 < m1[g][j]) ||
                                    (om1 == m1[g][j] && oidx < idx[g][j]);
                m2[g][j] = fminf(fminf(m2[g][j], om2), fmaxf(m1[g][j], om1));
                m1[g][j] = better ? om1 : m1[g][j];
                idx[g][j] = better ? oidx : idx[g][j];
            }
    }

    if (col == 0) {
        #pragma unroll
        for (int g = 0; g < 2; ++g)
            #pragma unroll
            for (int j = 0; j < 4; ++j) {
                const int row = rb * 32 + g * 16 + quad * 4 + j;
                unsigned u = __float_as_uint(m1[g][j]);
                u = (u & 0x80000000u) ? ~u : (u | 0x80000000u);      // order-preserving
                const unsigned short dh =
                    __half_as_ushort(__float2half(m2[g][j] - m1[g][j]));
                pk[((size_t)cz * NROWS + row) * KSUB + k] =
                    ((unsigned long long)u << 32) |
                    ((unsigned)dh << 16) | (unsigned)idx[g][j];
            }
    }
}

// ---------------- Kernel 3: finish = merge 4 splits + exact rescue + LUT output --------
__global__ __launch_bounds__(256) void finish_kernel(
    const float* __restrict__ xk, const float* __restrict__ ce,
    const float* __restrict__ cnorm, const unsigned long long* __restrict__ pk,
    const float* __restrict__ W3, const float* __restrict__ b3,
    float* __restrict__ out)
{
    __shared__ int codes_s[256];
    __shared__ int wl_s[256];
    __shared__ int wcnt;
    const int t = threadIdx.x;
    const int row0 = blockIdx.x * 32;
    if (t == 0) wcnt = 0;
    __syncthreads();

    // merge 4 splits for (row, k) = (row0 + t>>3, t&7)
    {
        const int row = row0 + (t >> 3);
        const int k = t & 7;
        unsigned long long p[4];
        #pragma unroll
        for (int s = 0; s < 4; ++s)
            p[s] = pk[((size_t)s * NROWS + row) * KSUB + k];
        unsigned long long w = p[0];
        #pragma unroll
        for (int s = 1; s < 4; ++s) w = p[s] < w ? p[s] : w;
        const unsigned uw = (unsigned)(w >> 32);
        const float m1w = __uint_as_float((uw & 0x80000000u) ? (uw ^ 0x80000000u) : ~uw);
        float m2g = m1w + (float)__ushort_as_half((unsigned short)((unsigned)w >> 16));
        #pragma unroll
        for (int s = 0; s < 4; ++s) {
            if (p[s] != w) {   // splits have disjoint idx ranges -> pk values unique
                const unsigned us = (unsigned)(p[s] >> 32);
                m2g = fminf(m2g, __uint_as_float(
                    (us & 0x80000000u) ? (us ^ 0x80000000u) : ~us));
            }
        }
        codes_s[t] = (int)(w & 0xFFFFull);
        if (m2g - m1w < FB_TAU) {      // near-tie: exact fp32 rescan needed
            const int slot = atomicAdd(&wcnt, 1);
            wl_s[slot] = t;
        }
    }
    __syncthreads();

    // exact fp32 rescue, wave-per-item over the block-local worklist
    {
        const int lane = t & 63;
        const int wid = t >> 6;
        const int nitems = wcnt;
        for (int i = wid; i < nitems; i += 4) {
            const int wg = wl_s[i];
            const int row = row0 + (wg >> 3), k = wg & 7;
            float xr[DSUB];
            {
                const float* xp = &xk[((size_t)k * NROWS + row) * DSUB];
                #pragma unroll
                for (int q = 0; q < DSUB; q += 4) {
                    const float4 v = *(const float4*)&xp[q];
                    xr[q + 0] = -2.f * v.x; xr[q + 1] = -2.f * v.y;
                    xr[q + 2] = -2.f * v.z; xr[q + 3] = -2.f * v.w;
                }
            }
            float bm = 1e30f; int bi = NC;
            for (int c = lane; c < NC; c += 64) {
                const float* cp = &ce[((size_t)k * NC + c) * DSUB];
                float s = cnorm[k * NC + c];
                #pragma unroll
                for (int d = 0; d < DSUB; ++d) s = fmaf(xr[d], cp[d], s);
                if (s < bm) { bm = s; bi = c; }
            }
            #pragma unroll
            for (int off = 1; off < 64; off <<= 1) {
                const float om = __shfl_xor(bm, off, 64);
                const int  oi = __shfl_xor(bi, off, 64);
                const bool better = (om < bm) || (om == bm && oi < bi);
                bm = better ? om : bm;
                bi = better ? oi : bi;
            }
            if (lane == 0) codes_s[wg] = bi;
        }
    }
    __syncthreads();

    // output: 32 rows x 6 = 192 outputs
    if (t < 32 * OUTD) {
        const int nl = t / OUTD;
        const int o = t - nl * OUTD;
        const int n = row0 + nl;
        float acc = b3[o];
        #pragma unroll
        for (int k = 0; k < KSUB; ++k) {
            const int code = codes_s[nl * KSUB + k];
            const float* cp = &ce[((size_t)k * NC + code) * DSUB];
            const float* wp = &W3[(k * DSUB) * OUTD + o];
            #pragma unroll
            for (int d = 0; d < DSUB; ++d)
                acc = fmaf(cp[d], wp[d * OUTD], acc);
        }
        out[n * OUTD + o] = acc;
    }
}

extern "C" void kernel_launch(void* const* d_in, const int* in_sizes, int n_in,
                              void* d_out, int out_size, void* d_ws, size_t ws_size,
                              hipStream_t stream)
{
    const float* z  = (const float*)d_in[0];
    const float* W1 = (const float*)d_in[1];
    const float* b1 = (const float*)d_in[2];
    const float* W2 = (const float*)d_in[3];
    const float* b2 = (const float*)d_in[4];
    const float* ce = (const float*)d_in[5];
    const float* W3 = (const float*)d_in[6];
    const float* b3 = (const float*)d_in[7];

    char* ws = (char*)d_ws;
    float* xk    = (float*)(ws + XK_OFF);
    float* cnorm = (float*)(ws + CN_OFF);
    f16x8* B1S   = (f16x8*)(ws + B1_OFF);
    unsigned long long* pk = (unsigned long long*)(ws + PK_OFF);

    hipLaunchKernelGGL(prep_kernel, dim3(512), dim3(256), 0, stream,
                       z, W1, b1, W2, b2, ce, xk, cnorm, B1S);
    hipLaunchKernelGGL(argmin_kernel, dim3(64, 8, 4), dim3(256), 0, stream,
                       xk, B1S, cnorm, pk);
    hipLaunchKernelGGL(finish_kernel, dim3(256), dim3(256), 0, stream,
                       xk, ce, cnorm, pk, W3, b3, (float*)d_out);
}